// Round 5
// baseline (501.913 us; speedup 1.0000x reference)
//
#include <hip/hip_runtime.h>

#define NN 50000
#define NE 800000
#define NG 512
#define INDIM 100
#define OUTD 24
#define NB_SCAN 196  // ceil(50000/256)

// bf16 raw-bits helpers (RNE pack)
__device__ inline float bf2f(unsigned short u) {
    unsigned v = (unsigned)u << 16;
    float f;
    __builtin_memcpy(&f, &v, 4);
    return f;
}
__device__ inline unsigned short f2bf(float f) {
    unsigned u;
    __builtin_memcpy(&u, &f, 4);
    u += 0x7fffu + ((u >> 16) & 1u);  // round-to-nearest-even
    return (unsigned short)(u >> 16);
}

// ---------------- CSR build ----------------

__global__ __launch_bounds__(256) void k_hist(const int* __restrict__ ei, int* __restrict__ deg) {
    unsigned e = blockIdx.x * 256u + threadIdx.x;
    if (e >= NE) return;
    atomicAdd(&deg[ei[NE + e]], 1);
}

__global__ __launch_bounds__(256) void k_scan1(const int* __restrict__ deg,
                                               int* __restrict__ rowptr,
                                               int* __restrict__ bsums) {
    __shared__ int s[256];
    int t = threadIdx.x;
    int i = blockIdx.x * 256 + t;
    int v = (i < NN) ? deg[i] : 0;
    s[t] = v;
    __syncthreads();
    for (int off = 1; off < 256; off <<= 1) {
        int u = (t >= off) ? s[t - off] : 0;
        __syncthreads();
        s[t] += u;
        __syncthreads();
    }
    if (i < NN) rowptr[i] = s[t] - v;
    if (t == 255) bsums[blockIdx.x] = s[255];
}

__global__ __launch_bounds__(256) void k_scan2(const int* __restrict__ bsums,
                                               int* __restrict__ boffs) {
    __shared__ int s[256];
    int t = threadIdx.x;
    int v = (t < NB_SCAN) ? bsums[t] : 0;
    s[t] = v;
    __syncthreads();
    for (int off = 1; off < 256; off <<= 1) {
        int u = (t >= off) ? s[t - off] : 0;
        __syncthreads();
        s[t] += u;
        __syncthreads();
    }
    if (t < NB_SCAN) boffs[t] = s[t] - v;
}

__global__ __launch_bounds__(256) void k_scan3(int* __restrict__ rowptr,
                                               int* __restrict__ cursor,
                                               const int* __restrict__ boffs) {
    int i = blockIdx.x * 256 + threadIdx.x;
    if (i >= NN) return;
    int v = rowptr[i] + boffs[blockIdx.x];
    rowptr[i] = v;
    cursor[i] = v;
    if (i == 0) rowptr[NN] = NE;
}

__global__ __launch_bounds__(256) void k_fill(const int* __restrict__ ei,
                                              int* __restrict__ cursor,
                                              int* __restrict__ csr) {
    unsigned e = blockIdx.x * 256u + threadIdx.x;
    if (e >= NE) return;
    int s = ei[e];
    int d = ei[NE + e];
    int pos = atomicAdd(&cursor[d], 1);
    csr[pos] = s;
}

// ---------------- y0 = x @ w1_0 (no bias), bf16 out ----------------

__global__ __launch_bounds__(256) void k_pre0(const float* __restrict__ x,
                                              const float* __restrict__ w1,
                                              unsigned short* __restrict__ y) {
    __shared__ float xs[4][INDIM];
    int sub = threadIdx.x >> 6, lane = threadIdx.x & 63;
    int n = blockIdx.x * 4 + sub;
    const float* xr = x + (size_t)n * INDIM;
    xs[sub][lane] = xr[lane];
    if (lane < INDIM - 64) xs[sub][64 + lane] = xr[64 + lane];
    __syncthreads();
    float a = 0.f;
#pragma unroll 4
    for (int k = 0; k < INDIM; ++k) a = fmaf(xs[sub][k], w1[k * 64 + lane], a);
    y[(size_t)n * 64 + lane] = f2bf(a);
}

// ---------------- fused layer ----------------
// y is bf16 (128B rows -> 6.4MB array, L2-friendly); accumulation in fp32.
// 16 gather loads in flight per wave.

template <bool HAS_NEXT, bool ADD_JK>
__global__ __launch_bounds__(256) void k_layer(const unsigned short* __restrict__ y,
                                               const int* __restrict__ rowptr,
                                               const int* __restrict__ csr,
                                               const float* __restrict__ b1,
                                               const float* __restrict__ w2,
                                               const float* __restrict__ b2,
                                               const float* __restrict__ wnext,
                                               const float* __restrict__ jkw,  // pre-offset
                                               unsigned short* __restrict__ ynext,
                                               float* __restrict__ jkacc,
                                               const float* __restrict__ jkb,
                                               const int* __restrict__ batch,
                                               float* __restrict__ g) {
    __shared__ float ts[4][64];
    __shared__ float hs[4][64];
    int sub = threadIdx.x >> 6, lane = threadIdx.x & 63;
    // wave-uniform node index -> rowptr/csr become scalar loads
    int n = __builtin_amdgcn_readfirstlane(blockIdx.x * 4 + sub);
    int beg = rowptr[n], end = rowptr[n + 1];
    float a[8];
    a[0] = bf2f(y[(size_t)n * 64 + lane]);
#pragma unroll
    for (int j = 1; j < 8; ++j) a[j] = 0.f;
    int e = beg;
    for (; e + 16 <= end; e += 16) {
        int idx[16];
#pragma unroll
        for (int j = 0; j < 16; ++j) idx[j] = csr[e + j];
        float v[16];
#pragma unroll
        for (int j = 0; j < 16; ++j) v[j] = bf2f(y[(size_t)idx[j] * 64 + lane]);
#pragma unroll
        for (int j = 0; j < 16; ++j) a[j & 7] += v[j];
    }
    if (e + 8 <= end) {
        int idx[8];
#pragma unroll
        for (int j = 0; j < 8; ++j) idx[j] = csr[e + j];
        float v[8];
#pragma unroll
        for (int j = 0; j < 8; ++j) v[j] = bf2f(y[(size_t)idx[j] * 64 + lane]);
#pragma unroll
        for (int j = 0; j < 8; ++j) a[j] += v[j];
        e += 8;
    }
    if (e + 4 <= end) {
        int i0 = csr[e], i1 = csr[e + 1], i2 = csr[e + 2], i3 = csr[e + 3];
        a[0] += bf2f(y[(size_t)i0 * 64 + lane]);
        a[1] += bf2f(y[(size_t)i1 * 64 + lane]);
        a[2] += bf2f(y[(size_t)i2 * 64 + lane]);
        a[3] += bf2f(y[(size_t)i3 * 64 + lane]);
        e += 4;
    }
    if (e + 2 <= end) {
        int i0 = csr[e], i1 = csr[e + 1];
        a[0] += bf2f(y[(size_t)i0 * 64 + lane]);
        a[1] += bf2f(y[(size_t)i1 * 64 + lane]);
        e += 2;
    }
    if (e < end) a[0] += bf2f(y[(size_t)csr[e] * 64 + lane]);
    float acc = ((a[0] + a[1]) + (a[2] + a[3])) + ((a[4] + a[5]) + (a[6] + a[7]));
    ts[sub][lane] = fmaxf(acc + b1[lane], 0.f);
    __syncthreads();
    float h = b2[lane];
#pragma unroll 8
    for (int k = 0; k < 64; ++k) h = fmaf(ts[sub][k], w2[k * 64 + lane], h);
    h = fmaxf(h, 0.f);  // inter-layer ReLU
    hs[sub][lane] = h;
    __syncthreads();
    float jk = ADD_JK ? jkacc[(size_t)n * 64 + lane] : 0.f;
    float yn = 0.f;
#pragma unroll 8
    for (int k = 0; k < 64; ++k) {
        float hk = hs[sub][k];
        jk = fmaf(hk, jkw[k * 64 + lane], jk);
        if (HAS_NEXT) yn = fmaf(hk, wnext[k * 64 + lane], yn);
    }
    if (HAS_NEXT) {
        jkacc[(size_t)n * 64 + lane] = jk;
        ynext[(size_t)n * 64 + lane] = f2bf(yn);
    } else {
        atomicAdd(&g[batch[n] * 64 + lane], jk + jkb[lane]);
    }
}

// ---------------- final head ----------------

__global__ __launch_bounds__(64) void k_final(const float* __restrict__ g,
                                              const float* __restrict__ w1,
                                              const float* __restrict__ b1,
                                              const float* __restrict__ bng,
                                              const float* __restrict__ bnb,
                                              const float* __restrict__ bnm,
                                              const float* __restrict__ bnv,
                                              const float* __restrict__ w2,
                                              const float* __restrict__ b2,
                                              const float* __restrict__ ow,
                                              const float* __restrict__ ob,
                                              float* __restrict__ out) {
    __shared__ float gs[64];
    __shared__ float t2[64];
    __shared__ float t3[64];
    int gr = blockIdx.x, lane = threadIdx.x;
    gs[lane] = g[gr * 64 + lane];
    __syncthreads();
    float acc = b1[lane];
#pragma unroll 8
    for (int k = 0; k < 64; ++k) acc = fmaf(gs[k], w1[k * 64 + lane], acc);
    acc = (acc - bnm[lane]) * rsqrtf(bnv[lane] + 1e-5f) * bng[lane] + bnb[lane];
    t2[lane] = fmaxf(acc, 0.f);
    __syncthreads();
    float acc2 = b2[lane];
#pragma unroll 8
    for (int k = 0; k < 64; ++k) acc2 = fmaf(t2[k], w2[k * 64 + lane], acc2);
    t3[lane] = acc2;
    __syncthreads();
    if (lane < OUTD) {
        float acc3 = ob[lane];
#pragma unroll 8
        for (int k = 0; k < 64; ++k) acc3 = fmaf(t3[k], ow[k * OUTD + lane], acc3);
        out[gr * OUTD + lane] = acc3;
    }
}

extern "C" void kernel_launch(void* const* d_in, const int* in_sizes, int n_in,
                              void* d_out, int out_size, void* d_ws, size_t ws_size,
                              hipStream_t stream) {
    const float* x     = (const float*)d_in[0];
    const int*   ei    = (const int*)d_in[1];
    const int*   batch = (const int*)d_in[2];
    const float* w1_0 = (const float*)d_in[3];
    const float* b1_0 = (const float*)d_in[4];
    const float* w2_0 = (const float*)d_in[5];
    const float* b2_0 = (const float*)d_in[6];
    const float* w1_1 = (const float*)d_in[7];
    const float* b1_1 = (const float*)d_in[8];
    const float* w2_1 = (const float*)d_in[9];
    const float* b2_1 = (const float*)d_in[10];
    const float* w1_2 = (const float*)d_in[11];
    const float* b1_2 = (const float*)d_in[12];
    const float* w2_2 = (const float*)d_in[13];
    const float* b2_2 = (const float*)d_in[14];
    const float* jk_w = (const float*)d_in[15];
    const float* jk_b = (const float*)d_in[16];
    const float* ffn_w1 = (const float*)d_in[17];
    const float* ffn_b1 = (const float*)d_in[18];
    const float* bn_g = (const float*)d_in[19];
    const float* bn_b = (const float*)d_in[20];
    const float* bn_m = (const float*)d_in[21];
    const float* bn_v = (const float*)d_in[22];
    const float* ffn_w2 = (const float*)d_in[23];
    const float* ffn_b2 = (const float*)d_in[24];
    const float* out_w  = (const float*)d_in[25];
    const float* out_b  = (const float*)d_in[26];

    // workspace layout
    float* ws = (float*)d_ws;
    unsigned short* ya = (unsigned short*)ws;          // 3.2M bf16
    unsigned short* yb = ya + 3200000;                 // 3.2M bf16
    float* jkacc = (float*)(yb + 3200000);             // 3.2M fp32
    float* g     = jkacc + 3200000;                    // 32768
    int*   deg    = (int*)(g + 32768);                 // 50000
    int*   rowptr = deg + NN;                          // 50001
    int*   cursor = rowptr + NN + 1;                   // 50000
    int*   csr    = cursor + NN;                       // 800000
    int*   bsums  = csr + NE;                          // 196
    int*   boffs  = bsums + NB_SCAN;                   // 196

    // ---- CSR build ----
    hipMemsetAsync(deg, 0, NN * sizeof(int), stream);
    hipMemsetAsync(g, 0, NG * 64 * sizeof(float), stream);
    k_hist<<<(NE + 255) / 256, 256, 0, stream>>>(ei, deg);
    k_scan1<<<NB_SCAN, 256, 0, stream>>>(deg, rowptr, bsums);
    k_scan2<<<1, 256, 0, stream>>>(bsums, boffs);
    k_scan3<<<NB_SCAN, 256, 0, stream>>>(rowptr, cursor, boffs);
    k_fill<<<(NE + 255) / 256, 256, 0, stream>>>(ei, cursor, csr);

    // ---- y0 = x @ w1_0 ----
    k_pre0<<<NN / 4, 256, 0, stream>>>(x, w1_0, ya);

    // ---- layer 0 ----
    k_layer<true, false><<<NN / 4, 256, 0, stream>>>(ya, rowptr, csr, b1_0, w2_0, b2_0,
                                                     w1_1, jk_w, yb, jkacc,
                                                     nullptr, nullptr, nullptr);
    // ---- layer 1 ----
    k_layer<true, true><<<NN / 4, 256, 0, stream>>>(yb, rowptr, csr, b1_1, w2_1, b2_1,
                                                    w1_2, jk_w + 64 * 64, ya, jkacc,
                                                    nullptr, nullptr, nullptr);
    // ---- layer 2: fused jk + pool ----
    k_layer<false, true><<<NN / 4, 256, 0, stream>>>(ya, rowptr, csr, b1_2, w2_2, b2_2,
                                                     nullptr, jk_w + 2 * 64 * 64, nullptr, jkacc,
                                                     jk_b, batch, g);

    // ---- head ----
    k_final<<<NG, 64, 0, stream>>>(g, ffn_w1, ffn_b1, bn_g, bn_b, bn_m, bn_v,
                                   ffn_w2, ffn_b2, out_w, out_b, (float*)d_out);
}

// Round 6
// 436.278 us; speedup vs baseline: 1.1504x; 1.1504x over previous
//
#include <hip/hip_runtime.h>

#define NN 50000
#define NE 800000
#define NG 512
#define INDIM 100
#define OUTD 24
#define NB_SCAN 196  // ceil(50000/256)
#define LROW 72      // padded LDS row (ushorts): 144B stride -> 4-bank advance, ~2-way (free)

typedef __attribute__((ext_vector_type(8))) short short8;
typedef __attribute__((ext_vector_type(4))) float floatx4;

// bf16 raw-bits helpers (RNE pack)
__device__ inline float bf2f(unsigned short u) {
    unsigned v = (unsigned)u << 16;
    float f;
    __builtin_memcpy(&f, &v, 4);
    return f;
}
__device__ inline unsigned short f2bf(float f) {
    unsigned u;
    __builtin_memcpy(&u, &f, 4);
    u += 0x7fffu + ((u >> 16) & 1u);  // round-to-nearest-even
    return (unsigned short)(u >> 16);
}

// ---------------- CSR build ----------------

__global__ __launch_bounds__(256) void k_hist(const int* __restrict__ ei, int* __restrict__ deg) {
    unsigned e = blockIdx.x * 256u + threadIdx.x;
    if (e >= NE) return;
    atomicAdd(&deg[ei[NE + e]], 1);
}

__global__ __launch_bounds__(256) void k_scan1(const int* __restrict__ deg,
                                               int* __restrict__ rowptr,
                                               int* __restrict__ bsums) {
    __shared__ int s[256];
    int t = threadIdx.x;
    int i = blockIdx.x * 256 + t;
    int v = (i < NN) ? deg[i] : 0;
    s[t] = v;
    __syncthreads();
    for (int off = 1; off < 256; off <<= 1) {
        int u = (t >= off) ? s[t - off] : 0;
        __syncthreads();
        s[t] += u;
        __syncthreads();
    }
    if (i < NN) rowptr[i] = s[t] - v;
    if (t == 255) bsums[blockIdx.x] = s[255];
}

__global__ __launch_bounds__(256) void k_scan2(const int* __restrict__ bsums,
                                               int* __restrict__ boffs) {
    __shared__ int s[256];
    int t = threadIdx.x;
    int v = (t < NB_SCAN) ? bsums[t] : 0;
    s[t] = v;
    __syncthreads();
    for (int off = 1; off < 256; off <<= 1) {
        int u = (t >= off) ? s[t - off] : 0;
        __syncthreads();
        s[t] += u;
        __syncthreads();
    }
    if (t < NB_SCAN) boffs[t] = s[t] - v;
}

__global__ __launch_bounds__(256) void k_scan3(int* __restrict__ rowptr,
                                               int* __restrict__ cursor,
                                               const int* __restrict__ boffs) {
    int i = blockIdx.x * 256 + threadIdx.x;
    if (i >= NN) return;
    int v = rowptr[i] + boffs[blockIdx.x];
    rowptr[i] = v;
    cursor[i] = v;
    if (i == 0) rowptr[NN] = NE;
}

__global__ __launch_bounds__(256) void k_fill(const int* __restrict__ ei,
                                              int* __restrict__ cursor,
                                              int* __restrict__ csr) {
    unsigned e = blockIdx.x * 256u + threadIdx.x;
    if (e >= NE) return;
    int s = ei[e];
    int d = ei[NE + e];
    int pos = atomicAdd(&cursor[d], 1);
    csr[pos] = s;
}

// ---------------- weight prep: 8 matrices fp32 [k][n] -> bf16 transposed [n][k] ----------------

__global__ __launch_bounds__(256) void k_wprep(const float* __restrict__ s0, const float* __restrict__ s1,
                                               const float* __restrict__ s2, const float* __restrict__ s3,
                                               const float* __restrict__ s4, const float* __restrict__ s5,
                                               const float* __restrict__ s6, const float* __restrict__ s7,
                                               unsigned short* __restrict__ dst) {
    const float* srcs[8] = {s0, s1, s2, s3, s4, s5, s6, s7};
    int id = blockIdx.x >> 4;                      // matrix index
    int off = ((blockIdx.x & 15) << 8) + threadIdx.x;  // 0..4095
    int k = off >> 6, n = off & 63;
    dst[id * 4096 + n * 64 + k] = f2bf(srcs[id][k * 64 + n]);
}

// ---------------- y0 = x @ w1_0 (no bias), bf16 out ----------------

__global__ __launch_bounds__(256) void k_pre0(const float* __restrict__ x,
                                              const float* __restrict__ w1,
                                              unsigned short* __restrict__ y) {
    __shared__ float xs[4][INDIM];
    int sub = threadIdx.x >> 6, lane = threadIdx.x & 63;
    int n = blockIdx.x * 4 + sub;
    const float* xr = x + (size_t)n * INDIM;
    xs[sub][lane] = xr[lane];
    if (lane < INDIM - 64) xs[sub][64 + lane] = xr[64 + lane];
    __syncthreads();
    float a = 0.f;
#pragma unroll 4
    for (int k = 0; k < INDIM; ++k) a = fmaf(xs[sub][k], w1[k * 64 + lane], a);
    y[(size_t)n * 64 + lane] = f2bf(a);
}

// ---------------- fused layer: gather-agg -> MFMA MLP -> jk (+ y_next) ----------------
// Block = 4 waves = 64 nodes. Gather (latency-bound, ILP-16) fills a bf16 LDS
// tile t = relu(z+b1); then three 64x64 GEMMs run on MFMA (weights as bf16
// B-fragments from L2 -- no per-node weight streaming, which was the R5 limiter).

template <bool HAS_NEXT, bool ADD_JK>
__global__ __launch_bounds__(256) void k_layer(const unsigned short* __restrict__ y,
                                               const int* __restrict__ rowptr,
                                               const int* __restrict__ csr,
                                               const float* __restrict__ b1,
                                               const unsigned short* __restrict__ w2T,  // bf16 [n][k]
                                               const float* __restrict__ b2,
                                               const unsigned short* __restrict__ wnT,  // bf16 [n][k]
                                               const unsigned short* __restrict__ jkT,  // bf16 [n][k]
                                               unsigned short* __restrict__ ynext,
                                               float* __restrict__ jkacc,
                                               const float* __restrict__ jkb,
                                               const int* __restrict__ batch,
                                               float* __restrict__ g) {
    __shared__ __align__(16) unsigned short tA[64 * LROW];
    __shared__ __align__(16) unsigned short tB[64 * LROW];
    int wave = threadIdx.x >> 6, lane = threadIdx.x & 63;
    int base = blockIdx.x * 64;
    float bias1 = b1[lane];

    // ---- gather phase: this wave fills rows wave*16 .. wave*16+15 of tA ----
    for (int i = 0; i < 16; ++i) {
        int node = base + wave * 16 + i;
        float t = 0.f;
        if (node < NN) {
            int nn = __builtin_amdgcn_readfirstlane(node);
            int beg = rowptr[nn], end = rowptr[nn + 1];
            float a[8];
            a[0] = bf2f(y[(size_t)nn * 64 + lane]);
#pragma unroll
            for (int j = 1; j < 8; ++j) a[j] = 0.f;
            int e = beg;
            for (; e + 16 <= end; e += 16) {
                int idx[16];
#pragma unroll
                for (int j = 0; j < 16; ++j) idx[j] = csr[e + j];
                float v[16];
#pragma unroll
                for (int j = 0; j < 16; ++j) v[j] = bf2f(y[(size_t)idx[j] * 64 + lane]);
#pragma unroll
                for (int j = 0; j < 16; ++j) a[j & 7] += v[j];
            }
            if (e + 8 <= end) {
                int idx[8];
#pragma unroll
                for (int j = 0; j < 8; ++j) idx[j] = csr[e + j];
#pragma unroll
                for (int j = 0; j < 8; ++j) a[j] += bf2f(y[(size_t)idx[j] * 64 + lane]);
                e += 8;
            }
            if (e + 4 <= end) {
                int i0 = csr[e], i1 = csr[e + 1], i2 = csr[e + 2], i3 = csr[e + 3];
                a[0] += bf2f(y[(size_t)i0 * 64 + lane]);
                a[1] += bf2f(y[(size_t)i1 * 64 + lane]);
                a[2] += bf2f(y[(size_t)i2 * 64 + lane]);
                a[3] += bf2f(y[(size_t)i3 * 64 + lane]);
                e += 4;
            }
            if (e + 2 <= end) {
                int i0 = csr[e], i1 = csr[e + 1];
                a[0] += bf2f(y[(size_t)i0 * 64 + lane]);
                a[1] += bf2f(y[(size_t)i1 * 64 + lane]);
                e += 2;
            }
            if (e < end) a[0] += bf2f(y[(size_t)csr[e] * 64 + lane]);
            float acc = ((a[0] + a[1]) + (a[2] + a[3])) + ((a[4] + a[5]) + (a[6] + a[7]));
            t = fmaxf(acc + bias1, 0.f);
        }
        tA[(wave * 16 + i) * LROW + lane] = f2bf(t);
    }
    __syncthreads();

    int quad = lane >> 4, l15 = lane & 15;
    int mrow = wave * 16 + l15;

    // ---- GEMM1: h = relu(t @ w2 + b2), bf16 into tB ----
    short8 a_k0 = *(const short8*)&tA[mrow * LROW + quad * 8];
    short8 a_k1 = *(const short8*)&tA[mrow * LROW + 32 + quad * 8];
#pragma unroll
    for (int nt = 0; nt < 4; ++nt) {
        int col = nt * 16 + l15;
        short8 b_k0 = *(const short8*)&w2T[col * 64 + quad * 8];
        short8 b_k1 = *(const short8*)&w2T[col * 64 + 32 + quad * 8];
        floatx4 c = {0.f, 0.f, 0.f, 0.f};
        c = __builtin_amdgcn_mfma_f32_16x16x32_bf16(a_k0, b_k0, c, 0, 0, 0);
        c = __builtin_amdgcn_mfma_f32_16x16x32_bf16(a_k1, b_k1, c, 0, 0, 0);
        float bb = b2[col];
#pragma unroll
        for (int r = 0; r < 4; ++r) {
            float v = fmaxf(c[r] + bb, 0.f);  // inter-layer ReLU is folded into jk/ynext consumers
            tB[(wave * 16 + quad * 4 + r) * LROW + col] = f2bf(v);
        }
    }
    __syncthreads();

    // ---- GEMM2: jk = h @ jkw (+ prev)  |  GEMM3: yn = h @ wnext ----
    short8 h_k0 = *(const short8*)&tB[mrow * LROW + quad * 8];
    short8 h_k1 = *(const short8*)&tB[mrow * LROW + 32 + quad * 8];
#pragma unroll
    for (int nt = 0; nt < 4; ++nt) {
        int col = nt * 16 + l15;
        short8 j_k0 = *(const short8*)&jkT[col * 64 + quad * 8];
        short8 j_k1 = *(const short8*)&jkT[col * 64 + 32 + quad * 8];
        floatx4 cj = {0.f, 0.f, 0.f, 0.f};
        cj = __builtin_amdgcn_mfma_f32_16x16x32_bf16(h_k0, j_k0, cj, 0, 0, 0);
        cj = __builtin_amdgcn_mfma_f32_16x16x32_bf16(h_k1, j_k1, cj, 0, 0, 0);
        if (HAS_NEXT) {
            short8 w_k0 = *(const short8*)&wnT[col * 64 + quad * 8];
            short8 w_k1 = *(const short8*)&wnT[col * 64 + 32 + quad * 8];
            floatx4 cy = {0.f, 0.f, 0.f, 0.f};
            cy = __builtin_amdgcn_mfma_f32_16x16x32_bf16(h_k0, w_k0, cy, 0, 0, 0);
            cy = __builtin_amdgcn_mfma_f32_16x16x32_bf16(h_k1, w_k1, cy, 0, 0, 0);
#pragma unroll
            for (int r = 0; r < 4; ++r) {
                int row = base + wave * 16 + quad * 4 + r;
                if (row < NN) {
                    float v = cj[r] + (ADD_JK ? jkacc[(size_t)row * 64 + col] : 0.f);
                    jkacc[(size_t)row * 64 + col] = v;
                    ynext[(size_t)row * 64 + col] = f2bf(cy[r]);
                }
            }
        } else {
            float jb = jkb[col];
#pragma unroll
            for (int r = 0; r < 4; ++r) {
                int row = base + wave * 16 + quad * 4 + r;
                if (row < NN) {
                    float v = cj[r] + (ADD_JK ? jkacc[(size_t)row * 64 + col] : 0.f) + jb;
                    atomicAdd(&g[batch[row] * 64 + col], v);
                }
            }
        }
    }
}

// ---------------- final head ----------------

__global__ __launch_bounds__(64) void k_final(const float* __restrict__ g,
                                              const float* __restrict__ w1,
                                              const float* __restrict__ b1,
                                              const float* __restrict__ bng,
                                              const float* __restrict__ bnb,
                                              const float* __restrict__ bnm,
                                              const float* __restrict__ bnv,
                                              const float* __restrict__ w2,
                                              const float* __restrict__ b2,
                                              const float* __restrict__ ow,
                                              const float* __restrict__ ob,
                                              float* __restrict__ out) {
    __shared__ float gs[64];
    __shared__ float t2[64];
    __shared__ float t3[64];
    int gr = blockIdx.x, lane = threadIdx.x;
    gs[lane] = g[gr * 64 + lane];
    __syncthreads();
    float acc = b1[lane];
#pragma unroll 8
    for (int k = 0; k < 64; ++k) acc = fmaf(gs[k], w1[k * 64 + lane], acc);
    acc = (acc - bnm[lane]) * rsqrtf(bnv[lane] + 1e-5f) * bng[lane] + bnb[lane];
    t2[lane] = fmaxf(acc, 0.f);
    __syncthreads();
    float acc2 = b2[lane];
#pragma unroll 8
    for (int k = 0; k < 64; ++k) acc2 = fmaf(t2[k], w2[k * 64 + lane], acc2);
    t3[lane] = acc2;
    __syncthreads();
    if (lane < OUTD) {
        float acc3 = ob[lane];
#pragma unroll 8
        for (int k = 0; k < 64; ++k) acc3 = fmaf(t3[k], ow[k * OUTD + lane], acc3);
        out[gr * OUTD + lane] = acc3;
    }
}

extern "C" void kernel_launch(void* const* d_in, const int* in_sizes, int n_in,
                              void* d_out, int out_size, void* d_ws, size_t ws_size,
                              hipStream_t stream) {
    const float* x     = (const float*)d_in[0];
    const int*   ei    = (const int*)d_in[1];
    const int*   batch = (const int*)d_in[2];
    const float* w1_0 = (const float*)d_in[3];
    const float* b1_0 = (const float*)d_in[4];
    const float* w2_0 = (const float*)d_in[5];
    const float* b2_0 = (const float*)d_in[6];
    const float* w1_1 = (const float*)d_in[7];
    const float* b1_1 = (const float*)d_in[8];
    const float* w2_1 = (const float*)d_in[9];
    const float* b2_1 = (const float*)d_in[10];
    const float* w1_2 = (const float*)d_in[11];
    const float* b1_2 = (const float*)d_in[12];
    const float* w2_2 = (const float*)d_in[13];
    const float* b2_2 = (const float*)d_in[14];
    const float* jk_w = (const float*)d_in[15];
    const float* jk_b = (const float*)d_in[16];
    const float* ffn_w1 = (const float*)d_in[17];
    const float* ffn_b1 = (const float*)d_in[18];
    const float* bn_g = (const float*)d_in[19];
    const float* bn_b = (const float*)d_in[20];
    const float* bn_m = (const float*)d_in[21];
    const float* bn_v = (const float*)d_in[22];
    const float* ffn_w2 = (const float*)d_in[23];
    const float* ffn_b2 = (const float*)d_in[24];
    const float* out_w  = (const float*)d_in[25];
    const float* out_b  = (const float*)d_in[26];

    // workspace layout
    float* ws = (float*)d_ws;
    unsigned short* ya = (unsigned short*)ws;          // 3.2M bf16
    unsigned short* yb = ya + 3200000;                 // 3.2M bf16
    float* jkacc = (float*)(yb + 3200000);             // 3.2M fp32
    float* g     = jkacc + 3200000;                    // 32768
    int*   deg    = (int*)(g + 32768);                 // 50000
    int*   rowptr = deg + NN;                          // 50001
    int*   cursor = rowptr + NN + 1;                   // 50000
    int*   csr    = cursor + NN;                       // 800000
    int*   bsums  = csr + NE;                          // 196
    int*   boffs  = bsums + NB_SCAN;                   // 196
    unsigned short* wT = (unsigned short*)(boffs + NB_SCAN + 4);  // 8 x 4096 bf16

    // ---- CSR build ----
    hipMemsetAsync(deg, 0, NN * sizeof(int), stream);
    hipMemsetAsync(g, 0, NG * 64 * sizeof(float), stream);
    k_hist<<<(NE + 255) / 256, 256, 0, stream>>>(ei, deg);
    k_scan1<<<NB_SCAN, 256, 0, stream>>>(deg, rowptr, bsums);
    k_scan2<<<1, 256, 0, stream>>>(bsums, boffs);
    k_scan3<<<NB_SCAN, 256, 0, stream>>>(rowptr, cursor, boffs);
    k_fill<<<(NE + 255) / 256, 256, 0, stream>>>(ei, cursor, csr);

    // ---- weight prep: w2_0,w2_1,w2_2, jk_l0,jk_l1,jk_l2, w1_1,w1_2 -> bf16 [n][k] ----
    k_wprep<<<128, 256, 0, stream>>>(w2_0, w2_1, w2_2,
                                     jk_w, jk_w + 4096, jk_w + 8192,
                                     w1_1, w1_2, wT);

    // ---- y0 = x @ w1_0 ----
    k_pre0<<<NN / 4, 256, 0, stream>>>(x, w1_0, ya);

    int nblk = (NN + 63) / 64;
    // ---- layer 0 ----
    k_layer<true, false><<<nblk, 256, 0, stream>>>(ya, rowptr, csr, b1_0,
                                                   wT + 0 * 4096, b2_0,
                                                   wT + 6 * 4096, wT + 3 * 4096,
                                                   yb, jkacc, nullptr, nullptr, nullptr);
    // ---- layer 1 ----
    k_layer<true, true><<<nblk, 256, 0, stream>>>(yb, rowptr, csr, b1_1,
                                                  wT + 1 * 4096, b2_1,
                                                  wT + 7 * 4096, wT + 4 * 4096,
                                                  ya, jkacc, nullptr, nullptr, nullptr);
    // ---- layer 2: fused jk + pool ----
    k_layer<false, true><<<nblk, 256, 0, stream>>>(ya, rowptr, csr, b1_2,
                                                   wT + 2 * 4096, b2_2,
                                                   nullptr, wT + 5 * 4096,
                                                   nullptr, jkacc, jk_b, batch, g);

    // ---- head ----
    k_final<<<NG, 64, 0, stream>>>(g, ffn_w1, ffn_b1, bn_g, bn_b, bn_m, bn_v,
                                   ffn_w2, ffn_b2, out_w, out_b, (float*)d_out);
}

// Round 7
// 406.279 us; speedup vs baseline: 1.2354x; 1.0738x over previous
//
#include <hip/hip_runtime.h>

#define NN 50000
#define NE 800000
#define NG 512
#define INDIM 100
#define OUTD 24
#define NB_SCAN 196  // ceil(50000/256)
#define LROW 72      // padded LDS row (ushorts): 144B stride

typedef __attribute__((ext_vector_type(8))) short short8;
typedef __attribute__((ext_vector_type(4))) float floatx4;

// bf16 raw-bits helpers (RNE pack)
__device__ inline float bf2f(unsigned short u) {
    unsigned v = (unsigned)u << 16;
    float f;
    __builtin_memcpy(&f, &v, 4);
    return f;
}
__device__ inline unsigned short f2bf(float f) {
    unsigned u;
    __builtin_memcpy(&u, &f, 4);
    u += 0x7fffu + ((u >> 16) & 1u);  // round-to-nearest-even
    return (unsigned short)(u >> 16);
}

// ---------------- CSR build ----------------

__global__ __launch_bounds__(256) void k_hist(const int* __restrict__ ei, int* __restrict__ deg) {
    unsigned e = blockIdx.x * 256u + threadIdx.x;
    if (e >= NE) return;
    atomicAdd(&deg[ei[NE + e]], 1);
}

__global__ __launch_bounds__(256) void k_scan1(const int* __restrict__ deg,
                                               int* __restrict__ rowptr,
                                               int* __restrict__ bsums) {
    __shared__ int s[256];
    int t = threadIdx.x;
    int i = blockIdx.x * 256 + t;
    int v = (i < NN) ? deg[i] : 0;
    s[t] = v;
    __syncthreads();
    for (int off = 1; off < 256; off <<= 1) {
        int u = (t >= off) ? s[t - off] : 0;
        __syncthreads();
        s[t] += u;
        __syncthreads();
    }
    if (i < NN) rowptr[i] = s[t] - v;
    if (t == 255) bsums[blockIdx.x] = s[255];
}

__global__ __launch_bounds__(256) void k_scan2(const int* __restrict__ bsums,
                                               int* __restrict__ boffs) {
    __shared__ int s[256];
    int t = threadIdx.x;
    int v = (t < NB_SCAN) ? bsums[t] : 0;
    s[t] = v;
    __syncthreads();
    for (int off = 1; off < 256; off <<= 1) {
        int u = (t >= off) ? s[t - off] : 0;
        __syncthreads();
        s[t] += u;
        __syncthreads();
    }
    if (t < NB_SCAN) boffs[t] = s[t] - v;
}

__global__ __launch_bounds__(256) void k_scan3(int* __restrict__ rowptr,
                                               int* __restrict__ cursor,
                                               const int* __restrict__ boffs) {
    int i = blockIdx.x * 256 + threadIdx.x;
    if (i >= NN) return;
    int v = rowptr[i] + boffs[blockIdx.x];
    rowptr[i] = v;
    cursor[i] = v;
    if (i == 0) rowptr[NN] = NE;
}

__global__ __launch_bounds__(256) void k_fill(const int* __restrict__ ei,
                                              int* __restrict__ cursor,
                                              int* __restrict__ csr) {
    unsigned e = blockIdx.x * 256u + threadIdx.x;
    if (e >= NE) return;
    int s = ei[e];
    int d = ei[NE + e];
    int pos = atomicAdd(&cursor[d], 1);
    csr[pos] = s;
}

// ---------------- weight prep: 8 matrices fp32 [k][n] -> bf16 transposed [n][k] ----------------

__global__ __launch_bounds__(256) void k_wprep(const float* __restrict__ s0, const float* __restrict__ s1,
                                               const float* __restrict__ s2, const float* __restrict__ s3,
                                               const float* __restrict__ s4, const float* __restrict__ s5,
                                               const float* __restrict__ s6, const float* __restrict__ s7,
                                               unsigned short* __restrict__ dst) {
    const float* srcs[8] = {s0, s1, s2, s3, s4, s5, s6, s7};
    int id = blockIdx.x >> 4;                          // matrix index
    int off = ((blockIdx.x & 15) << 8) + threadIdx.x;  // 0..4095
    int k = off >> 6, n = off & 63;
    dst[id * 4096 + n * 64 + k] = f2bf(srcs[id][k * 64 + n]);
}

// ---------------- y0 = x @ w1_0 (no bias), bf16 out ----------------

__global__ __launch_bounds__(256) void k_pre0(const float* __restrict__ x,
                                              const float* __restrict__ w1,
                                              unsigned short* __restrict__ y) {
    __shared__ float xs[4][INDIM];
    int sub = threadIdx.x >> 6, lane = threadIdx.x & 63;
    int n = blockIdx.x * 4 + sub;
    const float* xr = x + (size_t)n * INDIM;
    xs[sub][lane] = xr[lane];
    if (lane < INDIM - 64) xs[sub][64 + lane] = xr[64 + lane];
    __syncthreads();
    float a = 0.f;
#pragma unroll 4
    for (int k = 0; k < INDIM; ++k) a = fmaf(xs[sub][k], w1[k * 64 + lane], a);
    y[(size_t)n * 64 + lane] = f2bf(a);
}

// ---------------- fused layer: gather-agg -> MFMA MLP -> jk (+ y_next) ----------------
// Block = 8 waves (512 thr) = 64 nodes: R6's 4-wave version dropped occupancy
// to 25% and starved the latency-bound gather. 8 waves x 8 nodes each restores
// ~32 resident waves/CU (4 blocks x 18KB LDS). MFMA phase: 16 tiles, 2/wave.

template <bool HAS_NEXT, bool ADD_JK>
__global__ __launch_bounds__(512) void k_layer(const unsigned short* __restrict__ y,
                                               const int* __restrict__ rowptr,
                                               const int* __restrict__ csr,
                                               const float* __restrict__ b1,
                                               const unsigned short* __restrict__ w2T,  // bf16 [n][k]
                                               const float* __restrict__ b2,
                                               const unsigned short* __restrict__ wnT,  // bf16 [n][k]
                                               const unsigned short* __restrict__ jkT,  // bf16 [n][k]
                                               unsigned short* __restrict__ ynext,
                                               float* __restrict__ jkacc,
                                               const float* __restrict__ jkb,
                                               const int* __restrict__ batch,
                                               float* __restrict__ g) {
    __shared__ __align__(16) unsigned short tA[64 * LROW];
    __shared__ __align__(16) unsigned short tB[64 * LROW];
    int wave = threadIdx.x >> 6, lane = threadIdx.x & 63;
    int base = blockIdx.x * 64;
    float bias1 = b1[lane];

    // ---- gather phase: wave fills rows wave*8 .. wave*8+7 of tA ----
    for (int i = 0; i < 8; ++i) {
        int node = base + wave * 8 + i;
        float t = 0.f;
        if (node < NN) {
            int nn = __builtin_amdgcn_readfirstlane(node);
            int beg = rowptr[nn], end = rowptr[nn + 1];
            float a[8];
            a[0] = bf2f(y[(size_t)nn * 64 + lane]);
#pragma unroll
            for (int j = 1; j < 8; ++j) a[j] = 0.f;
            int e = beg;
            for (; e + 16 <= end; e += 16) {
                int idx[16];
#pragma unroll
                for (int j = 0; j < 16; ++j) idx[j] = csr[e + j];
                float v[16];
#pragma unroll
                for (int j = 0; j < 16; ++j) v[j] = bf2f(y[(size_t)idx[j] * 64 + lane]);
#pragma unroll
                for (int j = 0; j < 16; ++j) a[j & 7] += v[j];
            }
            if (e + 8 <= end) {
                int idx[8];
#pragma unroll
                for (int j = 0; j < 8; ++j) idx[j] = csr[e + j];
#pragma unroll
                for (int j = 0; j < 8; ++j) a[j] += bf2f(y[(size_t)idx[j] * 64 + lane]);
                e += 8;
            }
            if (e + 4 <= end) {
                int i0 = csr[e], i1 = csr[e + 1], i2 = csr[e + 2], i3 = csr[e + 3];
                a[0] += bf2f(y[(size_t)i0 * 64 + lane]);
                a[1] += bf2f(y[(size_t)i1 * 64 + lane]);
                a[2] += bf2f(y[(size_t)i2 * 64 + lane]);
                a[3] += bf2f(y[(size_t)i3 * 64 + lane]);
                e += 4;
            }
            if (e + 2 <= end) {
                int i0 = csr[e], i1 = csr[e + 1];
                a[0] += bf2f(y[(size_t)i0 * 64 + lane]);
                a[1] += bf2f(y[(size_t)i1 * 64 + lane]);
                e += 2;
            }
            if (e < end) a[0] += bf2f(y[(size_t)csr[e] * 64 + lane]);
            float acc = ((a[0] + a[1]) + (a[2] + a[3])) + ((a[4] + a[5]) + (a[6] + a[7]));
            t = fmaxf(acc + bias1, 0.f);
        }
        tA[(wave * 8 + i) * LROW + lane] = f2bf(t);
    }
    __syncthreads();

    int quad = lane >> 4, l15 = lane & 15;

    // ---- GEMM1: h = relu(t @ w2 + b2), bf16 into tB; 16 tiles, 2 per wave ----
#pragma unroll
    for (int tt = 0; tt < 2; ++tt) {
        int tile = wave * 2 + tt;
        int mt = tile >> 2, nt = tile & 3;
        int mrow = mt * 16 + l15;
        short8 a_k0 = *(const short8*)&tA[mrow * LROW + quad * 8];
        short8 a_k1 = *(const short8*)&tA[mrow * LROW + 32 + quad * 8];
        int col = nt * 16 + l15;
        short8 b_k0 = *(const short8*)&w2T[col * 64 + quad * 8];
        short8 b_k1 = *(const short8*)&w2T[col * 64 + 32 + quad * 8];
        floatx4 c = {0.f, 0.f, 0.f, 0.f};
        c = __builtin_amdgcn_mfma_f32_16x16x32_bf16(a_k0, b_k0, c, 0, 0, 0);
        c = __builtin_amdgcn_mfma_f32_16x16x32_bf16(a_k1, b_k1, c, 0, 0, 0);
        float bb = b2[col];
#pragma unroll
        for (int r = 0; r < 4; ++r) {
            float v = fmaxf(c[r] + bb, 0.f);  // inter-layer ReLU
            tB[(mt * 16 + quad * 4 + r) * LROW + col] = f2bf(v);
        }
    }
    __syncthreads();

    // ---- GEMM2: jk = h @ jkw (+ prev)  |  GEMM3: yn = h @ wnext ----
#pragma unroll
    for (int tt = 0; tt < 2; ++tt) {
        int tile = wave * 2 + tt;
        int mt = tile >> 2, nt = tile & 3;
        int mrow = mt * 16 + l15;
        short8 h_k0 = *(const short8*)&tB[mrow * LROW + quad * 8];
        short8 h_k1 = *(const short8*)&tB[mrow * LROW + 32 + quad * 8];
        int col = nt * 16 + l15;
        short8 j_k0 = *(const short8*)&jkT[col * 64 + quad * 8];
        short8 j_k1 = *(const short8*)&jkT[col * 64 + 32 + quad * 8];
        floatx4 cj = {0.f, 0.f, 0.f, 0.f};
        cj = __builtin_amdgcn_mfma_f32_16x16x32_bf16(h_k0, j_k0, cj, 0, 0, 0);
        cj = __builtin_amdgcn_mfma_f32_16x16x32_bf16(h_k1, j_k1, cj, 0, 0, 0);
        if (HAS_NEXT) {
            short8 w_k0 = *(const short8*)&wnT[col * 64 + quad * 8];
            short8 w_k1 = *(const short8*)&wnT[col * 64 + 32 + quad * 8];
            floatx4 cy = {0.f, 0.f, 0.f, 0.f};
            cy = __builtin_amdgcn_mfma_f32_16x16x32_bf16(h_k0, w_k0, cy, 0, 0, 0);
            cy = __builtin_amdgcn_mfma_f32_16x16x32_bf16(h_k1, w_k1, cy, 0, 0, 0);
#pragma unroll
            for (int r = 0; r < 4; ++r) {
                int row = base + mt * 16 + quad * 4 + r;
                if (row < NN) {
                    float v = cj[r] + (ADD_JK ? jkacc[(size_t)row * 64 + col] : 0.f);
                    jkacc[(size_t)row * 64 + col] = v;
                    ynext[(size_t)row * 64 + col] = f2bf(cy[r]);
                }
            }
        } else {
            float jb = jkb[col];
#pragma unroll
            for (int r = 0; r < 4; ++r) {
                int row = base + mt * 16 + quad * 4 + r;
                if (row < NN) {
                    float v = cj[r] + (ADD_JK ? jkacc[(size_t)row * 64 + col] : 0.f) + jb;
                    atomicAdd(&g[batch[row] * 64 + col], v);
                }
            }
        }
    }
}

// ---------------- final head ----------------

__global__ __launch_bounds__(64) void k_final(const float* __restrict__ g,
                                              const float* __restrict__ w1,
                                              const float* __restrict__ b1,
                                              const float* __restrict__ bng,
                                              const float* __restrict__ bnb,
                                              const float* __restrict__ bnm,
                                              const float* __restrict__ bnv,
                                              const float* __restrict__ w2,
                                              const float* __restrict__ b2,
                                              const float* __restrict__ ow,
                                              const float* __restrict__ ob,
                                              float* __restrict__ out) {
    __shared__ float gs[64];
    __shared__ float t2[64];
    __shared__ float t3[64];
    int gr = blockIdx.x, lane = threadIdx.x;
    gs[lane] = g[gr * 64 + lane];
    __syncthreads();
    float acc = b1[lane];
#pragma unroll 8
    for (int k = 0; k < 64; ++k) acc = fmaf(gs[k], w1[k * 64 + lane], acc);
    acc = (acc - bnm[lane]) * rsqrtf(bnv[lane] + 1e-5f) * bng[lane] + bnb[lane];
    t2[lane] = fmaxf(acc, 0.f);
    __syncthreads();
    float acc2 = b2[lane];
#pragma unroll 8
    for (int k = 0; k < 64; ++k) acc2 = fmaf(t2[k], w2[k * 64 + lane], acc2);
    t3[lane] = acc2;
    __syncthreads();
    if (lane < OUTD) {
        float acc3 = ob[lane];
#pragma unroll 8
        for (int k = 0; k < 64; ++k) acc3 = fmaf(t3[k], ow[k * OUTD + lane], acc3);
        out[gr * OUTD + lane] = acc3;
    }
}

extern "C" void kernel_launch(void* const* d_in, const int* in_sizes, int n_in,
                              void* d_out, int out_size, void* d_ws, size_t ws_size,
                              hipStream_t stream) {
    const float* x     = (const float*)d_in[0];
    const int*   ei    = (const int*)d_in[1];
    const int*   batch = (const int*)d_in[2];
    const float* w1_0 = (const float*)d_in[3];
    const float* b1_0 = (const float*)d_in[4];
    const float* w2_0 = (const float*)d_in[5];
    const float* b2_0 = (const float*)d_in[6];
    const float* w1_1 = (const float*)d_in[7];
    const float* b1_1 = (const float*)d_in[8];
    const float* w2_1 = (const float*)d_in[9];
    const float* b2_1 = (const float*)d_in[10];
    const float* w1_2 = (const float*)d_in[11];
    const float* b1_2 = (const float*)d_in[12];
    const float* w2_2 = (const float*)d_in[13];
    const float* b2_2 = (const float*)d_in[14];
    const float* jk_w = (const float*)d_in[15];
    const float* jk_b = (const float*)d_in[16];
    const float* ffn_w1 = (const float*)d_in[17];
    const float* ffn_b1 = (const float*)d_in[18];
    const float* bn_g = (const float*)d_in[19];
    const float* bn_b = (const float*)d_in[20];
    const float* bn_m = (const float*)d_in[21];
    const float* bn_v = (const float*)d_in[22];
    const float* ffn_w2 = (const float*)d_in[23];
    const float* ffn_b2 = (const float*)d_in[24];
    const float* out_w  = (const float*)d_in[25];
    const float* out_b  = (const float*)d_in[26];

    // workspace layout
    float* ws = (float*)d_ws;
    unsigned short* ya = (unsigned short*)ws;          // 3.2M bf16
    unsigned short* yb = ya + 3200000;                 // 3.2M bf16
    float* jkacc = (float*)(yb + 3200000);             // 3.2M fp32
    float* g     = jkacc + 3200000;                    // 32768
    int*   deg    = (int*)(g + 32768);                 // 50000
    int*   rowptr = deg + NN;                          // 50001
    int*   cursor = rowptr + NN + 1;                   // 50000
    int*   csr    = cursor + NN;                       // 800000
    int*   bsums  = csr + NE;                          // 196
    int*   boffs  = bsums + NB_SCAN;                   // 196
    unsigned short* wT = (unsigned short*)(boffs + NB_SCAN + 4);  // 8 x 4096 bf16

    // ---- CSR build ----
    hipMemsetAsync(deg, 0, NN * sizeof(int), stream);
    hipMemsetAsync(g, 0, NG * 64 * sizeof(float), stream);
    k_hist<<<(NE + 255) / 256, 256, 0, stream>>>(ei, deg);
    k_scan1<<<NB_SCAN, 256, 0, stream>>>(deg, rowptr, bsums);
    k_scan2<<<1, 256, 0, stream>>>(bsums, boffs);
    k_scan3<<<NB_SCAN, 256, 0, stream>>>(rowptr, cursor, boffs);
    k_fill<<<(NE + 255) / 256, 256, 0, stream>>>(ei, cursor, csr);

    // ---- weight prep: w2_0,w2_1,w2_2, jk_l0,jk_l1,jk_l2, w1_1,w1_2 -> bf16 [n][k] ----
    k_wprep<<<128, 256, 0, stream>>>(w2_0, w2_1, w2_2,
                                     jk_w, jk_w + 4096, jk_w + 8192,
                                     w1_1, w1_2, wT);

    // ---- y0 = x @ w1_0 ----
    k_pre0<<<NN / 4, 256, 0, stream>>>(x, w1_0, ya);

    int nblk = (NN + 63) / 64;
    // ---- layer 0 ----
    k_layer<true, false><<<nblk, 512, 0, stream>>>(ya, rowptr, csr, b1_0,
                                                   wT + 0 * 4096, b2_0,
                                                   wT + 6 * 4096, wT + 3 * 4096,
                                                   yb, jkacc, nullptr, nullptr, nullptr);
    // ---- layer 1 ----
    k_layer<true, true><<<nblk, 512, 0, stream>>>(yb, rowptr, csr, b1_1,
                                                  wT + 1 * 4096, b2_1,
                                                  wT + 7 * 4096, wT + 4 * 4096,
                                                  ya, jkacc, nullptr, nullptr, nullptr);
    // ---- layer 2: fused jk + pool ----
    k_layer<false, true><<<nblk, 512, 0, stream>>>(ya, rowptr, csr, b1_2,
                                                   wT + 2 * 4096, b2_2,
                                                   nullptr, wT + 5 * 4096,
                                                   nullptr, jkacc, jk_b, batch, g);

    // ---- head ----
    k_final<<<NG, 64, 0, stream>>>(g, ffn_w1, ffn_b1, bn_g, bn_b, bn_m, bn_v,
                                   ffn_w2, ffn_b2, out_w, out_b, (float*)d_out);
}

// Round 8
// 367.668 us; speedup vs baseline: 1.3651x; 1.1050x over previous
//
#include <hip/hip_runtime.h>

#define NN 50000
#define NE 800000
#define NG 512
#define INDIM 100
#define OUTD 24
#define NB_SCAN 196  // ceil(50000/256)
#define LROW 72      // padded LDS row (ushorts): 144B stride, 16B-aligned, 4-bank row advance
#define XROW 136     // padded LDS row for pre0 x-tile (ushorts): 272B stride, 16B-aligned

typedef __attribute__((ext_vector_type(8))) short short8;
typedef __attribute__((ext_vector_type(4))) float floatx4;

// bf16 raw-bits helpers (RNE pack)
__device__ inline float bf2f(unsigned short u) {
    unsigned v = (unsigned)u << 16;
    float f;
    __builtin_memcpy(&f, &v, 4);
    return f;
}
__device__ inline unsigned short f2bf(float f) {
    unsigned u;
    __builtin_memcpy(&u, &f, 4);
    u += 0x7fffu + ((u >> 16) & 1u);  // round-to-nearest-even
    return (unsigned short)(u >> 16);
}

// ---------------- CSR build ----------------

__global__ __launch_bounds__(256) void k_hist(const int* __restrict__ ei, int* __restrict__ deg) {
    unsigned e = blockIdx.x * 256u + threadIdx.x;
    if (e >= NE) return;
    atomicAdd(&deg[ei[NE + e]], 1);
}

__global__ __launch_bounds__(256) void k_scan1(const int* __restrict__ deg,
                                               int* __restrict__ rowptr,
                                               int* __restrict__ bsums) {
    __shared__ int s[256];
    int t = threadIdx.x;
    int i = blockIdx.x * 256 + t;
    int v = (i < NN) ? deg[i] : 0;
    s[t] = v;
    __syncthreads();
    for (int off = 1; off < 256; off <<= 1) {
        int u = (t >= off) ? s[t - off] : 0;
        __syncthreads();
        s[t] += u;
        __syncthreads();
    }
    if (i < NN) rowptr[i] = s[t] - v;
    if (t == 255) bsums[blockIdx.x] = s[255];
}

__global__ __launch_bounds__(256) void k_scan2(const int* __restrict__ bsums,
                                               int* __restrict__ boffs) {
    __shared__ int s[256];
    int t = threadIdx.x;
    int v = (t < NB_SCAN) ? bsums[t] : 0;
    s[t] = v;
    __syncthreads();
    for (int off = 1; off < 256; off <<= 1) {
        int u = (t >= off) ? s[t - off] : 0;
        __syncthreads();
        s[t] += u;
        __syncthreads();
    }
    if (t < NB_SCAN) boffs[t] = s[t] - v;
}

__global__ __launch_bounds__(256) void k_scan3(int* __restrict__ rowptr,
                                               int* __restrict__ cursor,
                                               const int* __restrict__ boffs) {
    int i = blockIdx.x * 256 + threadIdx.x;
    if (i >= NN) return;
    int v = rowptr[i] + boffs[blockIdx.x];
    rowptr[i] = v;
    cursor[i] = v;
    if (i == 0) rowptr[NN] = NE;
}

__global__ __launch_bounds__(256) void k_fill(const int* __restrict__ ei,
                                              int* __restrict__ cursor,
                                              int* __restrict__ csr) {
    unsigned e = blockIdx.x * 256u + threadIdx.x;
    if (e >= NE) return;
    int s = ei[e];
    int d = ei[NE + e];
    int pos = atomicAdd(&cursor[d], 1);
    csr[pos] = s;
}

// ---------------- weight prep ----------------
// 8 matrices fp32 [k][n] -> bf16 transposed [n][k]

__global__ __launch_bounds__(256) void k_wprep(const float* __restrict__ s0, const float* __restrict__ s1,
                                               const float* __restrict__ s2, const float* __restrict__ s3,
                                               const float* __restrict__ s4, const float* __restrict__ s5,
                                               const float* __restrict__ s6, const float* __restrict__ s7,
                                               unsigned short* __restrict__ dst) {
    const float* srcs[8] = {s0, s1, s2, s3, s4, s5, s6, s7};
    int id = blockIdx.x >> 4;                          // matrix index
    int off = ((blockIdx.x & 15) << 8) + threadIdx.x;  // 0..4095
    int k = off >> 6, n = off & 63;
    dst[id * 4096 + n * 64 + k] = f2bf(srcs[id][k * 64 + n]);
}

// w1_0 fp32 [100][64] -> bf16 transposed [64][128] (K zero-padded to 128)
__global__ __launch_bounds__(256) void k_wprep0(const float* __restrict__ w1,
                                                unsigned short* __restrict__ dst) {
    int i = blockIdx.x * 256 + threadIdx.x;  // 0..8191
    int n = i >> 7, k = i & 127;
    dst[n * 128 + k] = (k < INDIM) ? f2bf(w1[k * 64 + n]) : 0;
}

// ---------------- y0 = x @ w1_0 (no bias), MFMA, bf16 out ----------------
// 64 nodes/block; x tile bf16 in LDS (K padded to 128); w1T streamed from L2
// (14KB/block vs the 1.3GB/launch the per-wave matvec version streamed).

__global__ __launch_bounds__(256) void k_pre0(const float* __restrict__ x,
                                              const unsigned short* __restrict__ w1T,  // [64][128] bf16
                                              unsigned short* __restrict__ y) {
    __shared__ __align__(16) unsigned short xs[64 * XROW];
    int tid = threadIdx.x;
    int base = blockIdx.x * 64;
    for (int i = tid; i < 64 * 128; i += 256) {
        int r = i >> 7, c = i & 127;
        int node = base + r;
        float v = (c < INDIM && node < NN) ? x[(size_t)node * INDIM + c] : 0.f;
        xs[r * XROW + c] = f2bf(v);
    }
    __syncthreads();
    int wave = tid >> 6, lane = tid & 63;
    int quad = lane >> 4, l15 = lane & 15;
    int mt = wave;
#pragma unroll
    for (int nt = 0; nt < 4; ++nt) {
        floatx4 c = {0.f, 0.f, 0.f, 0.f};
#pragma unroll
        for (int kk = 0; kk < 4; ++kk) {
            short8 a = *(const short8*)&xs[(mt * 16 + l15) * XROW + kk * 32 + quad * 8];
            short8 b = *(const short8*)&w1T[(nt * 16 + l15) * 128 + kk * 32 + quad * 8];
            c = __builtin_amdgcn_mfma_f32_16x16x32_bf16(a, b, c, 0, 0, 0);
        }
        int col = nt * 16 + l15;
#pragma unroll
        for (int r = 0; r < 4; ++r) {
            int row = base + mt * 16 + quad * 4 + r;
            if (row < NN) y[(size_t)row * 64 + col] = f2bf(c[r]);
        }
    }
}

// ---------------- fused layer: gather-agg -> MFMA MLP -> jk (+ y_next) ----------------
// Block = 4 waves (256 thr) = 32 nodes -> grid 1563 (R7's 782x512 capped
// occupancy at 43% by grid-level block starvation; 8 blocks/CU now fit).

template <bool HAS_NEXT, bool ADD_JK>
__global__ __launch_bounds__(256) void k_layer(const unsigned short* __restrict__ y,
                                               const int* __restrict__ rowptr,
                                               const int* __restrict__ csr,
                                               const float* __restrict__ b1,
                                               const unsigned short* __restrict__ w2T,  // bf16 [n][k]
                                               const float* __restrict__ b2,
                                               const unsigned short* __restrict__ wnT,  // bf16 [n][k]
                                               const unsigned short* __restrict__ jkT,  // bf16 [n][k]
                                               unsigned short* __restrict__ ynext,
                                               float* __restrict__ jkacc,
                                               const float* __restrict__ jkb,
                                               const int* __restrict__ batch,
                                               float* __restrict__ g) {
    __shared__ __align__(16) unsigned short tA[32 * LROW];
    __shared__ __align__(16) unsigned short tB[32 * LROW];
    int wave = threadIdx.x >> 6, lane = threadIdx.x & 63;
    int base = blockIdx.x * 32;
    float bias1 = b1[lane];

    // ---- gather phase: wave fills rows wave*8 .. wave*8+7 of tA ----
    for (int i = 0; i < 8; ++i) {
        int node = base + wave * 8 + i;
        float t = 0.f;
        if (node < NN) {
            int nn = __builtin_amdgcn_readfirstlane(node);
            int beg = rowptr[nn], end = rowptr[nn + 1];
            float a[8];
            a[0] = bf2f(y[(size_t)nn * 64 + lane]);
#pragma unroll
            for (int j = 1; j < 8; ++j) a[j] = 0.f;
            int e = beg;
            for (; e + 16 <= end; e += 16) {
                int idx[16];
#pragma unroll
                for (int j = 0; j < 16; ++j) idx[j] = csr[e + j];
                float v[16];
#pragma unroll
                for (int j = 0; j < 16; ++j) v[j] = bf2f(y[(size_t)idx[j] * 64 + lane]);
#pragma unroll
                for (int j = 0; j < 16; ++j) a[j & 7] += v[j];
            }
            if (e + 8 <= end) {
                int idx[8];
#pragma unroll
                for (int j = 0; j < 8; ++j) idx[j] = csr[e + j];
#pragma unroll
                for (int j = 0; j < 8; ++j) a[j] += bf2f(y[(size_t)idx[j] * 64 + lane]);
                e += 8;
            }
            if (e + 4 <= end) {
                int i0 = csr[e], i1 = csr[e + 1], i2 = csr[e + 2], i3 = csr[e + 3];
                a[0] += bf2f(y[(size_t)i0 * 64 + lane]);
                a[1] += bf2f(y[(size_t)i1 * 64 + lane]);
                a[2] += bf2f(y[(size_t)i2 * 64 + lane]);
                a[3] += bf2f(y[(size_t)i3 * 64 + lane]);
                e += 4;
            }
            if (e + 2 <= end) {
                int i0 = csr[e], i1 = csr[e + 1];
                a[0] += bf2f(y[(size_t)i0 * 64 + lane]);
                a[1] += bf2f(y[(size_t)i1 * 64 + lane]);
                e += 2;
            }
            if (e < end) a[0] += bf2f(y[(size_t)csr[e] * 64 + lane]);
            float acc = ((a[0] + a[1]) + (a[2] + a[3])) + ((a[4] + a[5]) + (a[6] + a[7]));
            t = fmaxf(acc + bias1, 0.f);
        }
        tA[(wave * 8 + i) * LROW + lane] = f2bf(t);
    }
    __syncthreads();

    int quad = lane >> 4, l15 = lane & 15;

    // ---- GEMM1: h = relu(t @ w2 + b2), bf16 into tB; 8 tiles (2m x 4n), 2/wave ----
#pragma unroll
    for (int tt = 0; tt < 2; ++tt) {
        int tile = wave * 2 + tt;
        int mt = tile >> 2, nt = tile & 3;
        int mrow = mt * 16 + l15;
        short8 a_k0 = *(const short8*)&tA[mrow * LROW + quad * 8];
        short8 a_k1 = *(const short8*)&tA[mrow * LROW + 32 + quad * 8];
        int col = nt * 16 + l15;
        short8 b_k0 = *(const short8*)&w2T[col * 64 + quad * 8];
        short8 b_k1 = *(const short8*)&w2T[col * 64 + 32 + quad * 8];
        floatx4 c = {0.f, 0.f, 0.f, 0.f};
        c = __builtin_amdgcn_mfma_f32_16x16x32_bf16(a_k0, b_k0, c, 0, 0, 0);
        c = __builtin_amdgcn_mfma_f32_16x16x32_bf16(a_k1, b_k1, c, 0, 0, 0);
        float bb = b2[col];
#pragma unroll
        for (int r = 0; r < 4; ++r) {
            float v = fmaxf(c[r] + bb, 0.f);  // inter-layer ReLU
            tB[(mt * 16 + quad * 4 + r) * LROW + col] = f2bf(v);
        }
    }
    __syncthreads();

    // ---- GEMM2: jk = h @ jkw (+ prev)  |  GEMM3: yn = h @ wnext ----
#pragma unroll
    for (int tt = 0; tt < 2; ++tt) {
        int tile = wave * 2 + tt;
        int mt = tile >> 2, nt = tile & 3;
        int mrow = mt * 16 + l15;
        short8 h_k0 = *(const short8*)&tB[mrow * LROW + quad * 8];
        short8 h_k1 = *(const short8*)&tB[mrow * LROW + 32 + quad * 8];
        int col = nt * 16 + l15;
        short8 j_k0 = *(const short8*)&jkT[col * 64 + quad * 8];
        short8 j_k1 = *(const short8*)&jkT[col * 64 + 32 + quad * 8];
        floatx4 cj = {0.f, 0.f, 0.f, 0.f};
        cj = __builtin_amdgcn_mfma_f32_16x16x32_bf16(h_k0, j_k0, cj, 0, 0, 0);
        cj = __builtin_amdgcn_mfma_f32_16x16x32_bf16(h_k1, j_k1, cj, 0, 0, 0);
        if (HAS_NEXT) {
            short8 w_k0 = *(const short8*)&wnT[col * 64 + quad * 8];
            short8 w_k1 = *(const short8*)&wnT[col * 64 + 32 + quad * 8];
            floatx4 cy = {0.f, 0.f, 0.f, 0.f};
            cy = __builtin_amdgcn_mfma_f32_16x16x32_bf16(h_k0, w_k0, cy, 0, 0, 0);
            cy = __builtin_amdgcn_mfma_f32_16x16x32_bf16(h_k1, w_k1, cy, 0, 0, 0);
#pragma unroll
            for (int r = 0; r < 4; ++r) {
                int row = base + mt * 16 + quad * 4 + r;
                if (row < NN) {
                    float v = cj[r] + (ADD_JK ? jkacc[(size_t)row * 64 + col] : 0.f);
                    jkacc[(size_t)row * 64 + col] = v;
                    ynext[(size_t)row * 64 + col] = f2bf(cy[r]);
                }
            }
        } else {
            float jb = jkb[col];
#pragma unroll
            for (int r = 0; r < 4; ++r) {
                int row = base + mt * 16 + quad * 4 + r;
                if (row < NN) {
                    float v = cj[r] + (ADD_JK ? jkacc[(size_t)row * 64 + col] : 0.f) + jb;
                    atomicAdd(&g[batch[row] * 64 + col], v);
                }
            }
        }
    }
}

// ---------------- final head ----------------

__global__ __launch_bounds__(64) void k_final(const float* __restrict__ g,
                                              const float* __restrict__ w1,
                                              const float* __restrict__ b1,
                                              const float* __restrict__ bng,
                                              const float* __restrict__ bnb,
                                              const float* __restrict__ bnm,
                                              const float* __restrict__ bnv,
                                              const float* __restrict__ w2,
                                              const float* __restrict__ b2,
                                              const float* __restrict__ ow,
                                              const float* __restrict__ ob,
                                              float* __restrict__ out) {
    __shared__ float gs[64];
    __shared__ float t2[64];
    __shared__ float t3[64];
    int gr = blockIdx.x, lane = threadIdx.x;
    gs[lane] = g[gr * 64 + lane];
    __syncthreads();
    float acc = b1[lane];
#pragma unroll 8
    for (int k = 0; k < 64; ++k) acc = fmaf(gs[k], w1[k * 64 + lane], acc);
    acc = (acc - bnm[lane]) * rsqrtf(bnv[lane] + 1e-5f) * bng[lane] + bnb[lane];
    t2[lane] = fmaxf(acc, 0.f);
    __syncthreads();
    float acc2 = b2[lane];
#pragma unroll 8
    for (int k = 0; k < 64; ++k) acc2 = fmaf(t2[k], w2[k * 64 + lane], acc2);
    t3[lane] = acc2;
    __syncthreads();
    if (lane < OUTD) {
        float acc3 = ob[lane];
#pragma unroll 8
        for (int k = 0; k < 64; ++k) acc3 = fmaf(t3[k], ow[k * OUTD + lane], acc3);
        out[gr * OUTD + lane] = acc3;
    }
}

extern "C" void kernel_launch(void* const* d_in, const int* in_sizes, int n_in,
                              void* d_out, int out_size, void* d_ws, size_t ws_size,
                              hipStream_t stream) {
    const float* x     = (const float*)d_in[0];
    const int*   ei    = (const int*)d_in[1];
    const int*   batch = (const int*)d_in[2];
    const float* w1_0 = (const float*)d_in[3];
    const float* b1_0 = (const float*)d_in[4];
    const float* w2_0 = (const float*)d_in[5];
    const float* b2_0 = (const float*)d_in[6];
    const float* w1_1 = (const float*)d_in[7];
    const float* b1_1 = (const float*)d_in[8];
    const float* w2_1 = (const float*)d_in[9];
    const float* b2_1 = (const float*)d_in[10];
    const float* w1_2 = (const float*)d_in[11];
    const float* b1_2 = (const float*)d_in[12];
    const float* w2_2 = (const float*)d_in[13];
    const float* b2_2 = (const float*)d_in[14];
    const float* jk_w = (const float*)d_in[15];
    const float* jk_b = (const float*)d_in[16];
    const float* ffn_w1 = (const float*)d_in[17];
    const float* ffn_b1 = (const float*)d_in[18];
    const float* bn_g = (const float*)d_in[19];
    const float* bn_b = (const float*)d_in[20];
    const float* bn_m = (const float*)d_in[21];
    const float* bn_v = (const float*)d_in[22];
    const float* ffn_w2 = (const float*)d_in[23];
    const float* ffn_b2 = (const float*)d_in[24];
    const float* out_w  = (const float*)d_in[25];
    const float* out_b  = (const float*)d_in[26];

    // workspace layout
    float* ws = (float*)d_ws;
    unsigned short* ya = (unsigned short*)ws;          // 3.2M bf16
    unsigned short* yb = ya + 3200000;                 // 3.2M bf16
    float* jkacc = (float*)(yb + 3200000);             // 3.2M fp32
    float* g     = jkacc + 3200000;                    // 32768
    int*   deg    = (int*)(g + 32768);                 // 50000
    int*   rowptr = deg + NN;                          // 50001
    int*   cursor = rowptr + NN + 1;                   // 50000
    int*   csr    = cursor + NN;                       // 800000
    int*   bsums  = csr + NE;                          // 196
    int*   boffs  = bsums + NB_SCAN;                   // 196
    unsigned short* wT  = (unsigned short*)(boffs + NB_SCAN + 4);  // 8 x 4096 bf16
    unsigned short* w0T = wT + 8 * 4096;                           // 64 x 128 bf16

    // ---- CSR build ----
    hipMemsetAsync(deg, 0, NN * sizeof(int), stream);
    hipMemsetAsync(g, 0, NG * 64 * sizeof(float), stream);
    k_hist<<<(NE + 255) / 256, 256, 0, stream>>>(ei, deg);
    k_scan1<<<NB_SCAN, 256, 0, stream>>>(deg, rowptr, bsums);
    k_scan2<<<1, 256, 0, stream>>>(bsums, boffs);
    k_scan3<<<NB_SCAN, 256, 0, stream>>>(rowptr, cursor, boffs);
    k_fill<<<(NE + 255) / 256, 256, 0, stream>>>(ei, cursor, csr);

    // ---- weight prep ----
    k_wprep<<<128, 256, 0, stream>>>(w2_0, w2_1, w2_2,
                                     jk_w, jk_w + 4096, jk_w + 8192,
                                     w1_1, w1_2, wT);
    k_wprep0<<<32, 256, 0, stream>>>(w1_0, w0T);

    // ---- y0 = x @ w1_0 (MFMA) ----
    k_pre0<<<(NN + 63) / 64, 256, 0, stream>>>(x, w0T, ya);

    int nblk = (NN + 31) / 32;
    // ---- layer 0 ----
    k_layer<true, false><<<nblk, 256, 0, stream>>>(ya, rowptr, csr, b1_0,
                                                   wT + 0 * 4096, b2_0,
                                                   wT + 6 * 4096, wT + 3 * 4096,
                                                   yb, jkacc, nullptr, nullptr, nullptr);
    // ---- layer 1 ----
    k_layer<true, true><<<nblk, 256, 0, stream>>>(yb, rowptr, csr, b1_1,
                                                  wT + 1 * 4096, b2_1,
                                                  wT + 7 * 4096, wT + 4 * 4096,
                                                  ya, jkacc, nullptr, nullptr, nullptr);
    // ---- layer 2: fused jk + pool ----
    k_layer<false, true><<<nblk, 256, 0, stream>>>(ya, rowptr, csr, b1_2,
                                                   wT + 2 * 4096, b2_2,
                                                   nullptr, wT + 5 * 4096,
                                                   nullptr, jkacc, jk_b, batch, g);

    // ---- head ----
    k_final<<<NG, 64, 0, stream>>>(g, ffn_w1, ffn_b1, bn_g, bn_b, bn_m, bn_v,
                                   ffn_w2, ffn_b2, out_w, out_b, (float*)d_out);
}